// Round 3
// baseline (2668.297 us; speedup 1.0000x reference)
//
#include <hip/hip_runtime.h>
#include <hip/hip_bf16.h>

#define NN 50000
#define EE 800000
#define TT 3

// ws layout (float offsets) — total 4,451,744 floats = 17.0 MiB
#define OFF_C1   0            // 3*64*8 = 1536
#define OFF_C2   1536         // 3*64   = 192
#define OFF_NS1  1728         // N*8    = 400000
#define OFF_H    401728       // N*64   = 3200000
#define OFF_NS2  3601728      // N      = 50000
#define OFF_H2   3651728      // N*16   = 800000
#define OFF_OACC 4451728      // 16
#define ZERO_OFF 1728
#define ZERO_CNT 4450016      // NS1 through OACC end; divisible by 4

__global__ void zero_k(float* ws) {
    size_t i = ((size_t)blockIdx.x * 256 + threadIdx.x) * 4;
    if (i < ZERO_CNT) {
        *(float4*)(ws + ZERO_OFF + i) = make_float4(0.f, 0.f, 0.f, 0.f);
    }
}

// C1[t][k][h] = sum_k2 W1[t][k][k2] * sum_j (al1+ar1)[t][k2][h*8+j]
// c2[t][k]   = sum_k2 W2[t][k][k2] * sum_j (al2+ar2)[t][k2][j]
__global__ void precompute(const float* __restrict__ W1, const float* __restrict__ al1,
                           const float* __restrict__ ar1, const float* __restrict__ W2,
                           const float* __restrict__ al2, const float* __restrict__ ar2,
                           float* __restrict__ ws) {
    __shared__ float a1c[64][8];
    __shared__ float a2c[16];
    int t = blockIdx.x;
    int tid = threadIdx.x;
    {
        int k2 = tid >> 3, hh = tid & 7;
        float s = 0.f;
#pragma unroll
        for (int j = 0; j < 8; ++j) {
            int idx = t * 4096 + k2 * 64 + hh * 8 + j;
            s += al1[idx] + ar1[idx];
        }
        a1c[k2][hh] = s;
    }
    if (tid < 16) {
        float s = 0.f;
#pragma unroll
        for (int j = 0; j < 16; ++j) {
            int idx = t * 256 + tid * 16 + j;
            s += al2[idx] + ar2[idx];
        }
        a2c[tid] = s;
    }
    __syncthreads();
    {
        int k = tid >> 3, hh = tid & 7;
        float s = 0.f;
#pragma unroll
        for (int k2 = 0; k2 < 64; ++k2)
            s += W1[t * 4096 + k * 64 + k2] * a1c[k2][hh];
        ws[OFF_C1 + t * 512 + k * 8 + hh] = s;
    }
    if (tid < 64) {
        float s = 0.f;
#pragma unroll
        for (int k2 = 0; k2 < 16; ++k2)
            s += W2[t * 1024 + tid * 16 + k2] * a2c[k2];
        ws[OFF_C2 + t * 64 + tid] = s;
    }
}

// layer0 softmax denominators: ns1[d][h] += exp(leaky(x[src] . C1[t][:,h]))
__global__ __launch_bounds__(256) void logits1(const float* __restrict__ x, const int* __restrict__ src,
                        const int* __restrict__ dst, const int* __restrict__ etype,
                        float* __restrict__ ws) {
    __shared__ alignas(16) float C1s[1536];
    int tid = threadIdx.x;
    for (int q = tid; q < 1536; q += 256) C1s[q] = ws[OFF_C1 + q];
    __syncthreads();
    int e = blockIdx.x * 256 + tid;
    if (e >= EE) return;
    int s = src[e], d = dst[e], t = etype[e];
    const float4* xr = (const float4*)(x + (size_t)s * 64);
    const float* C = C1s + t * 512;
    float acc[8] = {0,0,0,0,0,0,0,0};
#pragma unroll
    for (int kc = 0; kc < 16; ++kc) {
        float4 u = xr[kc];
        float m[4] = {u.x, u.y, u.z, u.w};
#pragma unroll
        for (int j = 0; j < 4; ++j) {
            int k = kc * 4 + j;
            float4 c0 = *(const float4*)(C + k * 8);
            float4 c1 = *(const float4*)(C + k * 8 + 4);
            acc[0] += m[j]*c0.x; acc[1] += m[j]*c0.y; acc[2] += m[j]*c0.z; acc[3] += m[j]*c0.w;
            acc[4] += m[j]*c1.x; acc[5] += m[j]*c1.y; acc[6] += m[j]*c1.z; acc[7] += m[j]*c1.w;
        }
    }
    float* ns1 = ws + OFF_NS1 + (size_t)d * 8;
#pragma unroll
    for (int hh = 0; hh < 8; ++hh) {
        float v = acc[hh];
        v = v > 0.f ? v : 0.2f * v;
        atomicAdd(ns1 + hh, __expf(v));
    }
}

// layer0 aggregation: 8 lanes per edge (lane = head). logit + feat recomputed,
// msg scattered by atomics into H.
__global__ __launch_bounds__(256) void aggregate1(const float* __restrict__ x, const int* __restrict__ src,
                           const int* __restrict__ dst, const int* __restrict__ etype,
                           const float* __restrict__ W1, float* __restrict__ ws) {
    __shared__ alignas(16) float Wls[3 * 4104];  // 64x64 per type, +8 pad per type
    __shared__ alignas(16) float C1s[1536];
    int tid = threadIdx.x;
    for (int q = tid; q < 12288; q += 256) {
        int t = q >> 12;
        Wls[q + t * 8] = W1[q];
    }
    for (int q = tid; q < 1536; q += 256) C1s[q] = ws[OFF_C1 + q];
    __syncthreads();
    int e = blockIdx.x * 32 + (tid >> 3);
    int hh = tid & 7;
    if (e >= EE) return;
    int s = src[e], d = dst[e], t = etype[e];
    const float4* xr = (const float4*)(x + (size_t)s * 64);
    const float* Wb = Wls + t * 4104;
    const float* Cc = C1s + t * 512 + hh;
    float acc[8] = {0,0,0,0,0,0,0,0};
    float lg = 0.f;
#pragma unroll
    for (int kc = 0; kc < 16; ++kc) {
        float4 u = xr[kc];
        float m[4] = {u.x, u.y, u.z, u.w};
#pragma unroll
        for (int j = 0; j < 4; ++j) {
            int k = kc * 4 + j;
            const float* wr = Wb + k * 64 + hh * 8;
            float4 w0 = *(const float4*)wr;
            float4 w1 = *(const float4*)(wr + 4);
            lg += m[j] * Cc[k * 8];
            acc[0] += m[j]*w0.x; acc[1] += m[j]*w0.y; acc[2] += m[j]*w0.z; acc[3] += m[j]*w0.w;
            acc[4] += m[j]*w1.x; acc[5] += m[j]*w1.y; acc[6] += m[j]*w1.z; acc[7] += m[j]*w1.w;
        }
    }
    lg = lg > 0.f ? lg : 0.2f * lg;
    float w = __expf(lg) / ws[OFF_NS1 + (size_t)d * 8 + hh];
    float* hrow = ws + OFF_H + (size_t)d * 64 + hh * 8;
#pragma unroll
    for (int j = 0; j < 8; ++j) atomicAdd(hrow + j, acc[j] * w);
}

__global__ void elu_k(float* ws) {
    int i = blockIdx.x * 256 + threadIdx.x;
    if (i >= NN * 64) return;
    float v = ws[OFF_H + i];
    ws[OFF_H + i] = v > 0.f ? v : __expf(v) - 1.f;
}

// h2[i][c] = res_b[c] + sum_k h[i][k] * res_w[k][c]
__global__ __launch_bounds__(256) void resid_k(const float* __restrict__ res_w, const float* __restrict__ res_b,
                        float* __restrict__ ws) {
    __shared__ alignas(16) float Wr[1024];
    __shared__ float Br[16];
    int tid = threadIdx.x;
    for (int q = tid; q < 1024; q += 256) Wr[q] = res_w[q];
    if (tid < 16) Br[tid] = res_b[tid];
    __syncthreads();
    int g = blockIdx.x * 256 + tid;
    if (g >= NN * 16) return;
    int i = g >> 4, c = g & 15;
    const float4* hr = (const float4*)(ws + OFF_H + (size_t)i * 64);
    float acc = Br[c];
#pragma unroll
    for (int k4 = 0; k4 < 16; ++k4) {
        float4 h4 = hr[k4];
        acc += h4.x * Wr[(k4*4+0)*16 + c];
        acc += h4.y * Wr[(k4*4+1)*16 + c];
        acc += h4.z * Wr[(k4*4+2)*16 + c];
        acc += h4.w * Wr[(k4*4+3)*16 + c];
    }
    ws[OFF_H2 + g] = acc;
}

// layer1 softmax denominators
__global__ __launch_bounds__(256) void logits2(const int* __restrict__ src, const int* __restrict__ dst,
                        const int* __restrict__ etype, float* __restrict__ ws) {
    __shared__ alignas(16) float c2s[192];
    int tid = threadIdx.x;
    if (tid < 192) c2s[tid] = ws[OFF_C2 + tid];
    __syncthreads();
    int e = blockIdx.x * 256 + tid;
    if (e >= EE) return;
    int s = src[e], d = dst[e], t = etype[e];
    const float4* hr = (const float4*)(ws + OFF_H + (size_t)s * 64);
    const float* C = c2s + t * 64;
    float acc = 0.f;
#pragma unroll
    for (int k4 = 0; k4 < 16; ++k4) {
        float4 h4 = hr[k4];
        float4 c4 = *(const float4*)(C + k4 * 4);
        acc += h4.x*c4.x + h4.y*c4.y + h4.z*c4.z + h4.w*c4.w;
    }
    acc = acc > 0.f ? acc : 0.2f * acc;
    atomicAdd(ws + OFF_NS2 + d, __expf(acc));
}

// layer1 aggregation: 1 thread per edge; logit recomputed; 16 atomics per edge
__global__ __launch_bounds__(256) void aggregate2(const int* __restrict__ src, const int* __restrict__ dst,
                           const int* __restrict__ etype, const float* __restrict__ W2,
                           float* __restrict__ ws) {
    __shared__ alignas(16) float Wls[3 * 1032];  // 64x16 per type, +8 pad per type
    __shared__ alignas(16) float c2s[192];
    int tid = threadIdx.x;
    for (int q = tid; q < 3072; q += 256) {
        int t = q >> 10;
        Wls[q + t * 8] = W2[q];
    }
    if (tid < 192) c2s[tid] = ws[OFF_C2 + tid];
    __syncthreads();
    int e = blockIdx.x * 256 + tid;
    if (e >= EE) return;
    int s = src[e], d = dst[e], t = etype[e];
    const float4* hr = (const float4*)(ws + OFF_H + (size_t)s * 64);
    const float* Wb = Wls + t * 1032;
    const float* C = c2s + t * 64;
    float acc[16];
#pragma unroll
    for (int c = 0; c < 16; ++c) acc[c] = 0.f;
    float lg = 0.f;
#pragma unroll
    for (int k4 = 0; k4 < 16; ++k4) {
        float4 m4 = hr[k4];
        float4 c4 = *(const float4*)(C + k4 * 4);
        lg += m4.x*c4.x + m4.y*c4.y + m4.z*c4.z + m4.w*c4.w;
        float mm[4] = {m4.x, m4.y, m4.z, m4.w};
#pragma unroll
        for (int j = 0; j < 4; ++j) {
            const float* wr = Wb + (k4 * 4 + j) * 16;
            float4 a0 = ((const float4*)wr)[0];
            float4 a1 = ((const float4*)wr)[1];
            float4 a2 = ((const float4*)wr)[2];
            float4 a3 = ((const float4*)wr)[3];
            acc[0]+=mm[j]*a0.x; acc[1]+=mm[j]*a0.y; acc[2]+=mm[j]*a0.z; acc[3]+=mm[j]*a0.w;
            acc[4]+=mm[j]*a1.x; acc[5]+=mm[j]*a1.y; acc[6]+=mm[j]*a1.z; acc[7]+=mm[j]*a1.w;
            acc[8]+=mm[j]*a2.x; acc[9]+=mm[j]*a2.y; acc[10]+=mm[j]*a2.z; acc[11]+=mm[j]*a2.w;
            acc[12]+=mm[j]*a3.x; acc[13]+=mm[j]*a3.y; acc[14]+=mm[j]*a3.z; acc[15]+=mm[j]*a3.w;
        }
    }
    lg = lg > 0.f ? lg : 0.2f * lg;
    float w = __expf(lg) / ws[OFF_NS2 + d];
    float* orow = ws + OFF_H2 + (size_t)d * 16;
#pragma unroll
    for (int c = 0; c < 16; ++c) atomicAdd(orow + c, acc[c] * w);
}

__global__ void mean_k(float* ws) {
    __shared__ float part[16][17];
    int tid = threadIdx.x;
    int c = tid & 15, r = tid >> 4;
    float s = 0.f;
    for (int i = blockIdx.x * 16 + r; i < NN; i += gridDim.x * 16)
        s += ws[OFF_H2 + (size_t)i * 16 + c];
    part[r][c] = s;
    __syncthreads();
    if (tid < 16) {
        float t = 0.f;
#pragma unroll
        for (int r2 = 0; r2 < 16; ++r2) t += part[r2][tid];
        atomicAdd(ws + OFF_OACC + tid, t);
    }
}

__global__ void final_k(float* ws, float* out) {
    int c = threadIdx.x;
    if (c < 16) out[c] = ws[OFF_OACC + c] * (1.0f / (float)NN);
}

extern "C" void kernel_launch(void* const* d_in, const int* in_sizes, int n_in,
                              void* d_out, int out_size, void* d_ws, size_t ws_size,
                              hipStream_t stream) {
    const float* x     = (const float*)d_in[0];
    const int*   src   = (const int*)d_in[1];
    const int*   dst   = (const int*)d_in[2];
    // d_in[3] = ntype (unused by reference)
    const int*   etype = (const int*)d_in[4];
    const float* W1    = (const float*)d_in[5];
    const float* al1   = (const float*)d_in[6];
    const float* ar1   = (const float*)d_in[7];
    const float* W2    = (const float*)d_in[8];
    const float* al2   = (const float*)d_in[9];
    const float* ar2   = (const float*)d_in[10];
    const float* res_w = (const float*)d_in[11];
    const float* res_b = (const float*)d_in[12];
    float* ws = (float*)d_ws;
    float* out = (float*)d_out;

    hipLaunchKernelGGL(zero_k, dim3((ZERO_CNT / 4 + 255) / 256), dim3(256), 0, stream, ws);
    hipLaunchKernelGGL(precompute, dim3(TT), dim3(512), 0, stream, W1, al1, ar1, W2, al2, ar2, ws);
    hipLaunchKernelGGL(logits1, dim3(EE / 256), dim3(256), 0, stream, x, src, dst, etype, ws);
    hipLaunchKernelGGL(aggregate1, dim3(EE / 32), dim3(256), 0, stream, x, src, dst, etype, W1, ws);
    hipLaunchKernelGGL(elu_k, dim3(NN * 64 / 256), dim3(256), 0, stream, ws);
    hipLaunchKernelGGL(resid_k, dim3(NN * 16 / 256), dim3(256), 0, stream, res_w, res_b, ws);
    hipLaunchKernelGGL(logits2, dim3(EE / 256), dim3(256), 0, stream, src, dst, etype, ws);
    hipLaunchKernelGGL(aggregate2, dim3(EE / 256), dim3(256), 0, stream, src, dst, etype, W2, ws);
    hipLaunchKernelGGL(mean_k, dim3(256), dim3(256), 0, stream, ws);
    hipLaunchKernelGGL(final_k, dim3(1), dim3(64), 0, stream, ws, out);
}

// Round 4
// 680.352 us; speedup vs baseline: 3.9219x; 3.9219x over previous
//
#include <hip/hip_runtime.h>
#include <hip/hip_bf16.h>

typedef unsigned int u32;

#define NN 50000
#define EE 800000
#define TT 3

// ws layout (dword offsets) — total 8,151,748 dwords = 32.6 MiB
#define OFF_C1     0         // 1536 f
#define OFF_C2     1536      // 192 f
#define OFF_CNT    1728      // 50000 i  (zeroed each call)
#define OFF_ROWPTR 51728     // 50004 i
#define OFF_CNT2   101732    // 50000 i
#define OFF_PSRC   151732    // 800000 i (src | etype<<20, dst-sorted)
#define OFF_EA1    951732    // E*8 bf16 = 3,200,000 dwords (16B-aligned)
#define OFF_H      4151732   // N*64 f (16B-aligned)
#define OFF_H2     7351732   // N*16 f (16B-aligned)
#define OFF_OACC   8151732   // 16 f

__device__ __forceinline__ float bflo(u32 p) {
    union { u32 i; float f; } v; v.i = p << 16; return v.f;
}
__device__ __forceinline__ float bfhi(u32 p) {
    union { u32 i; float f; } v; v.i = p & 0xffff0000u; return v.f;
}
__device__ __forceinline__ u32 f2bf(float f) {  // RNE to bf16 (low 16 bits)
    union { float f; u32 i; } v; v.f = f;
    return (v.i + 0x7fffu + ((v.i >> 16) & 1u)) >> 16;
}

__global__ void zero_k(int* wsi, float* ws) {
    int i = blockIdx.x * 256 + threadIdx.x;
    if (i < NN) wsi[OFF_CNT + i] = 0;
    if (i < 16) ws[OFF_OACC + i] = 0.f;
}

// C1[t][k][h] = sum_k2 W1[t][k][k2] * sum_j (al1+ar1)[t][k2][h*8+j]
// c2[t][k]   = sum_k2 W2[t][k][k2] * sum_j (al2+ar2)[t][k2][j]
__global__ void precompute(const float* __restrict__ W1, const float* __restrict__ al1,
                           const float* __restrict__ ar1, const float* __restrict__ W2,
                           const float* __restrict__ al2, const float* __restrict__ ar2,
                           float* __restrict__ ws) {
    __shared__ float a1c[64][8];
    __shared__ float a2c[16];
    int t = blockIdx.x;
    int tid = threadIdx.x;
    {
        int k2 = tid >> 3, hh = tid & 7;
        float s = 0.f;
#pragma unroll
        for (int j = 0; j < 8; ++j) {
            int idx = t * 4096 + k2 * 64 + hh * 8 + j;
            s += al1[idx] + ar1[idx];
        }
        a1c[k2][hh] = s;
    }
    if (tid < 16) {
        float s = 0.f;
#pragma unroll
        for (int j = 0; j < 16; ++j) {
            int idx = t * 256 + tid * 16 + j;
            s += al2[idx] + ar2[idx];
        }
        a2c[tid] = s;
    }
    __syncthreads();
    {
        int k = tid >> 3, hh = tid & 7;
        float s = 0.f;
#pragma unroll
        for (int k2 = 0; k2 < 64; ++k2)
            s += W1[t * 4096 + k * 64 + k2] * a1c[k2][hh];
        ws[OFF_C1 + t * 512 + k * 8 + hh] = s;
    }
    if (tid < 64) {
        float s = 0.f;
#pragma unroll
        for (int k2 = 0; k2 < 16; ++k2)
            s += W2[t * 1024 + tid * 16 + k2] * a2c[k2];
        ws[OFF_C2 + t * 64 + tid] = s;
    }
}

__global__ __launch_bounds__(256) void hist_k(const int* __restrict__ dst, int* wsi) {
    int e = blockIdx.x * 256 + threadIdx.x;
    if (e < EE) atomicAdd(wsi + OFF_CNT + dst[e], 1);
}

// single-block exclusive scan of cnt -> rowptr (and cnt2 = rowptr copy for scatter)
__global__ __launch_bounds__(1024) void scan_k(int* wsi) {
    __shared__ int ps[1024];
    const int CH = 49;  // 1024*49 >= 50000
    int tid = threadIdx.x;
    int base = tid * CH;
    int sum = 0;
    for (int j = 0; j < CH; ++j) {
        int idx = base + j;
        if (idx < NN) sum += wsi[OFF_CNT + idx];
    }
    ps[tid] = sum;
    __syncthreads();
    for (int off = 1; off < 1024; off <<= 1) {
        int v = (tid >= off) ? ps[tid - off] : 0;
        __syncthreads();
        ps[tid] += v;
        __syncthreads();
    }
    int run = ps[tid] - sum;  // exclusive prefix
    for (int j = 0; j < CH; ++j) {
        int idx = base + j;
        if (idx < NN) {
            wsi[OFF_ROWPTR + idx] = run;
            wsi[OFF_CNT2 + idx] = run;
            run += wsi[OFF_CNT + idx];
        }
    }
    if (tid == 1023) wsi[OFF_ROWPTR + NN] = EE;
}

__global__ __launch_bounds__(256) void scatter_k(const int* __restrict__ src, const int* __restrict__ dst,
                          const int* __restrict__ etype, int* wsi) {
    int e = blockIdx.x * 256 + threadIdx.x;
    if (e >= EE) return;
    int d = dst[e];
    int slot = atomicAdd(wsi + OFF_CNT2 + d, 1);
    wsi[OFF_PSRC + slot] = src[e] | (etype[e] << 20);
}

// layer0 logits over sorted slots: store exp(leaky(x[src].C1[t][:,h])) as 8 bf16 / slot
__global__ __launch_bounds__(256) void logits1p(const float* __restrict__ x, const int* __restrict__ wsi,
                         float* __restrict__ ws) {
    __shared__ alignas(16) float C1s[1536];
    int tid = threadIdx.x;
    for (int q = tid; q < 1536; q += 256) C1s[q] = ws[OFF_C1 + q];
    __syncthreads();
    int e = blockIdx.x * 256 + tid;
    if (e >= EE) return;
    int p = wsi[OFF_PSRC + e];
    int sn = p & 0xFFFFF, t = p >> 20;
    const float4* xr = (const float4*)(x + (size_t)sn * 64);
    const float* C = C1s + t * 512;
    float acc[8] = {0,0,0,0,0,0,0,0};
#pragma unroll
    for (int kc = 0; kc < 16; ++kc) {
        float4 u = xr[kc];
        float m[4] = {u.x, u.y, u.z, u.w};
#pragma unroll
        for (int j = 0; j < 4; ++j) {
            int k = kc * 4 + j;
            float4 c0 = *(const float4*)(C + k * 8);
            float4 c1 = *(const float4*)(C + k * 8 + 4);
            acc[0] += m[j]*c0.x; acc[1] += m[j]*c0.y; acc[2] += m[j]*c0.z; acc[3] += m[j]*c0.w;
            acc[4] += m[j]*c1.x; acc[5] += m[j]*c1.y; acc[6] += m[j]*c1.z; acc[7] += m[j]*c1.w;
        }
    }
    u32 r[8];
#pragma unroll
    for (int hh = 0; hh < 8; ++hh) {
        float v = acc[hh];
        v = v > 0.f ? v : 0.2f * v;
        r[hh] = f2bf(__expf(v));
    }
    uint4 o;
    o.x = r[0] | (r[1] << 16);
    o.y = r[2] | (r[3] << 16);
    o.z = r[4] | (r[5] << 16);
    o.w = r[6] | (r[7] << 16);
    ((uint4*)(ws + OFF_EA1))[e] = o;
}

// layer0 fused softmax+aggregate: one wave per dst. lane = output channel c.
// y[t][h][k] accumulated in regs (lane=k), GEMV with W1 applied once per dst.
__global__ __launch_bounds__(256) void agg1(const float* __restrict__ x, const float* __restrict__ W1,
                     const int* __restrict__ wsi, float* __restrict__ ws) {
    __shared__ alignas(16) float ys[4][3 * 8 * 72];  // 27648 B
    int tid = threadIdx.x;
    int wave = tid >> 6, lane = tid & 63;
    int d = blockIdx.x * 4 + wave;
    int start = wsi[OFF_ROWPTR + d], end = wsi[OFF_ROWPTR + d + 1];
    float y[3][8];
    float den[8];
#pragma unroll
    for (int t = 0; t < 3; ++t)
#pragma unroll
        for (int h = 0; h < 8; ++h) y[t][h] = 0.f;
#pragma unroll
    for (int h = 0; h < 8; ++h) den[h] = 0.f;
    const uint4* ea = (const uint4*)(ws + OFF_EA1);
    for (int s = start; s < end; ++s) {
        int p = wsi[OFF_PSRC + s];
        int sn = p & 0xFFFFF, t = p >> 20;
        float m = x[(size_t)sn * 64 + lane];
        uint4 wq = ea[s];
        float w[8];
        w[0]=bflo(wq.x); w[1]=bfhi(wq.x); w[2]=bflo(wq.y); w[3]=bfhi(wq.y);
        w[4]=bflo(wq.z); w[5]=bfhi(wq.z); w[6]=bflo(wq.w); w[7]=bfhi(wq.w);
#pragma unroll
        for (int h = 0; h < 8; ++h) den[h] += w[h];
        if (t == 0) {
#pragma unroll
            for (int h = 0; h < 8; ++h) y[0][h] += w[h] * m;
        } else if (t == 1) {
#pragma unroll
            for (int h = 0; h < 8; ++h) y[1][h] += w[h] * m;
        } else {
#pragma unroll
            for (int h = 0; h < 8; ++h) y[2][h] += w[h] * m;
        }
    }
    float* my = ys[wave];
#pragma unroll
    for (int t = 0; t < 3; ++t)
#pragma unroll
        for (int h = 0; h < 8; ++h) my[(t * 8 + h) * 72 + lane] = y[t][h];
    // epilogue: out_c = sum_t sum_k y[t][h(c)][k] * W1[t][k][c]  (no barrier: own wave's data)
    int h = lane >> 3;
    float acc = 0.f;
#pragma unroll
    for (int t = 0; t < 3; ++t) {
        const float* yt = my + (t * 8 + h) * 72;
        const float* Wt = W1 + t * 4096 + lane;
#pragma unroll
        for (int k4 = 0; k4 < 16; ++k4) {
            float4 y4 = *(const float4*)(yt + k4 * 4);
            acc += y4.x * Wt[(k4 * 4 + 0) * 64];
            acc += y4.y * Wt[(k4 * 4 + 1) * 64];
            acc += y4.z * Wt[(k4 * 4 + 2) * 64];
            acc += y4.w * Wt[(k4 * 4 + 3) * 64];
        }
    }
    float dn = den[0];
    if (h == 1) dn = den[1];
    if (h == 2) dn = den[2];
    if (h == 3) dn = den[3];
    if (h == 4) dn = den[4];
    if (h == 5) dn = den[5];
    if (h == 6) dn = den[6];
    if (h == 7) dn = den[7];
    float v = (end > start) ? acc / dn : 0.f;
    v = v > 0.f ? v : __expf(v) - 1.f;  // ELU fused
    ws[OFF_H + (size_t)d * 64 + lane] = v;
}

// h2[i][c] = res_b[c] + sum_k h[i][k] * res_w[k][c]   (residual pre-pass, all nodes)
__global__ __launch_bounds__(256) void resid_k(const float* __restrict__ res_w, const float* __restrict__ res_b,
                        float* __restrict__ ws) {
    __shared__ alignas(16) float Wr[1024];
    __shared__ float Br[16];
    int tid = threadIdx.x;
    for (int q = tid; q < 1024; q += 256) Wr[q] = res_w[q];
    if (tid < 16) Br[tid] = res_b[tid];
    __syncthreads();
    int g = blockIdx.x * 256 + tid;
    if (g >= NN * 16) return;
    int i = g >> 4, c = g & 15;
    const float4* hr = (const float4*)(ws + OFF_H + (size_t)i * 64);
    float acc = Br[c];
#pragma unroll
    for (int k4 = 0; k4 < 16; ++k4) {
        float4 h4 = hr[k4];
        acc += h4.x * Wr[(k4*4+0)*16 + c];
        acc += h4.y * Wr[(k4*4+1)*16 + c];
        acc += h4.z * Wr[(k4*4+2)*16 + c];
        acc += h4.w * Wr[(k4*4+3)*16 + c];
    }
    ws[OFF_H2 + g] = acc;
}

// layer1 fused: one wave per dst; logit via in-wave butterfly; adds into resid H2.
__global__ __launch_bounds__(256) void agg2(const float* __restrict__ W2, const int* __restrict__ wsi,
                     float* __restrict__ ws) {
    __shared__ alignas(16) float ys2[4][3 * 72];
    __shared__ alignas(16) float c2s[192];
    int tid = threadIdx.x;
    if (tid < 192) c2s[tid] = ws[OFF_C2 + tid];
    __syncthreads();
    int wave = tid >> 6, lane = tid & 63;
    int d = blockIdx.x * 4 + wave;
    int start = wsi[OFF_ROWPTR + d], end = wsi[OFF_ROWPTR + d + 1];
    if (end <= start) return;  // H2 row stays = residual (matches segment_sum=0)
    float y0 = 0.f, y1 = 0.f, y2 = 0.f, den = 0.f;
    for (int s = start; s < end; ++s) {
        int p = wsi[OFF_PSRC + s];
        int sn = p & 0xFFFFF, t = p >> 20;
        float m = ws[OFF_H + (size_t)sn * 64 + lane];
        float prod = m * c2s[t * 64 + lane];
#pragma unroll
        for (int mask = 1; mask < 64; mask <<= 1) prod += __shfl_xor(prod, mask);
        float lg = prod > 0.f ? prod : 0.2f * prod;
        float w = __expf(lg);
        den += w;
        if (t == 0) y0 += w * m;
        else if (t == 1) y1 += w * m;
        else y2 += w * m;
    }
    float* my = ys2[wave];
    my[0 * 72 + lane] = y0;
    my[1 * 72 + lane] = y1;
    my[2 * 72 + lane] = y2;
    int q = lane >> 4, c = lane & 15;
    float acc = 0.f;
#pragma unroll
    for (int t = 0; t < 3; ++t) {
#pragma unroll
        for (int kk = 0; kk < 4; ++kk) {
            float4 y4 = *(const float4*)(my + t * 72 + q * 16 + kk * 4);
            const float* Wt = W2 + t * 1024 + (q * 16 + kk * 4) * 16 + c;
            acc += y4.x * Wt[0];
            acc += y4.y * Wt[16];
            acc += y4.z * Wt[32];
            acc += y4.w * Wt[48];
        }
    }
    acc += __shfl_xor(acc, 16);
    acc += __shfl_xor(acc, 32);
    if (q == 0) {
        float* o = ws + OFF_H2 + (size_t)d * 16 + c;
        *o = *o + acc / den;
    }
}

__global__ void mean_k(float* ws) {
    __shared__ float part[16][17];
    int tid = threadIdx.x;
    int c = tid & 15, r = tid >> 4;
    float s = 0.f;
    for (int i = blockIdx.x * 16 + r; i < NN; i += gridDim.x * 16)
        s += ws[OFF_H2 + (size_t)i * 16 + c];
    part[r][c] = s;
    __syncthreads();
    if (tid < 16) {
        float t = 0.f;
#pragma unroll
        for (int r2 = 0; r2 < 16; ++r2) t += part[r2][tid];
        atomicAdd(ws + OFF_OACC + tid, t);
    }
}

__global__ void final_k(float* ws, float* out) {
    int c = threadIdx.x;
    if (c < 16) out[c] = ws[OFF_OACC + c] * (1.0f / (float)NN);
}

extern "C" void kernel_launch(void* const* d_in, const int* in_sizes, int n_in,
                              void* d_out, int out_size, void* d_ws, size_t ws_size,
                              hipStream_t stream) {
    const float* x     = (const float*)d_in[0];
    const int*   src   = (const int*)d_in[1];
    const int*   dst   = (const int*)d_in[2];
    // d_in[3] = ntype (unused by reference)
    const int*   etype = (const int*)d_in[4];
    const float* W1    = (const float*)d_in[5];
    const float* al1   = (const float*)d_in[6];
    const float* ar1   = (const float*)d_in[7];
    const float* W2    = (const float*)d_in[8];
    const float* al2   = (const float*)d_in[9];
    const float* ar2   = (const float*)d_in[10];
    const float* res_w = (const float*)d_in[11];
    const float* res_b = (const float*)d_in[12];
    float* ws = (float*)d_ws;
    int* wsi = (int*)d_ws;
    float* out = (float*)d_out;

    hipLaunchKernelGGL(zero_k, dim3((NN + 255) / 256), dim3(256), 0, stream, wsi, ws);
    hipLaunchKernelGGL(precompute, dim3(TT), dim3(512), 0, stream, W1, al1, ar1, W2, al2, ar2, ws);
    hipLaunchKernelGGL(hist_k, dim3((EE + 255) / 256), dim3(256), 0, stream, dst, wsi);
    hipLaunchKernelGGL(scan_k, dim3(1), dim3(1024), 0, stream, wsi);
    hipLaunchKernelGGL(scatter_k, dim3((EE + 255) / 256), dim3(256), 0, stream, src, dst, etype, wsi);
    hipLaunchKernelGGL(logits1p, dim3(EE / 256), dim3(256), 0, stream, x, wsi, ws);
    hipLaunchKernelGGL(agg1, dim3(NN / 4), dim3(256), 0, stream, x, W1, wsi, ws);
    hipLaunchKernelGGL(resid_k, dim3(NN * 16 / 256), dim3(256), 0, stream, res_w, res_b, ws);
    hipLaunchKernelGGL(agg2, dim3(NN / 4), dim3(256), 0, stream, W2, wsi, ws);
    hipLaunchKernelGGL(mean_k, dim3(256), dim3(256), 0, stream, ws);
    hipLaunchKernelGGL(final_k, dim3(1), dim3(64), 0, stream, ws, out);
}